// Round 5
// baseline (288.130 us; speedup 1.0000x reference)
//
#include <hip/hip_runtime.h>
#include <hip/hip_bf16.h>

#define TPB 256

typedef float f2 __attribute__((ext_vector_type(2)));

// ws layout (fp32):
//   W[grp*256 + j*32 + k] = w1[j][grp*32 + k]   grp: 0 = u*m, 1 = u, 2 = m
//   W[768 + j] = b1[j];  W[776 + j] = w2[j];  W[784] = b2
// k-contiguous: float2 pair {W[..][2d], W[..][2d+1]} is an aligned 8 B load
// at a wave-uniform address -> scalar pipe, off the VALU path.

__global__ void prep_kernel(const float* __restrict__ w1,
                            const float* __restrict__ b1,
                            const float* __restrict__ w2,
                            const float* __restrict__ b2,
                            float* __restrict__ W) {
    int t = threadIdx.x;
    for (int i = t; i < 768; i += TPB) {
        int grp = i >> 8;
        int r   = i & 255;
        int j   = r >> 5;
        int k   = r & 31;
        W[i] = w1[j * 96 + grp * 32 + k];
    }
    if (t < 8) W[768 + t] = b1[t];
    if (t < 8) W[776 + t] = w2[t];
    if (t == 0) W[784]    = b2[0];
}

// Cooperative gather: 8 lanes x float4 load one 128 B row contiguously.
// Swizzled LDS transpose (pos = c ^ (e&7)) is bank-conflict-free both ways.
__global__ __launch_bounds__(TPB, 4) void mf_kernel(
    const int* __restrict__ users, const int* __restrict__ movies,
    const float4* __restrict__ uemb,   // [1e6][8] float4 (32 fp32/row)
    const float4* __restrict__ memb,   // [1e5][8]
    const float* __restrict__ W,
    float* __restrict__ out, int n) {
    __shared__ float4 buf[TPB * 8];    // 32 KB: element e, chunk-pos p at buf[e*8+p]
    __shared__ int sidx[2][TPB];

    int t = threadIdx.x;
    int i = blockIdx.x * TPB + t;
    int ic = (i < n) ? i : (n - 1);
    sidx[0][t] = users[ic];
    sidx[1][t] = movies[ic];
    __syncthreads();

    int r = t >> 3;          // row-slot 0..31 within each cooperative load
    int c = t & 7;           // 16 B chunk 0..7 within a row

    // ---- user rows: cooperative gather -> swizzled LDS ----
    float4 st[8];
#pragma unroll
    for (int s = 0; s < 8; ++s) {
        int row = sidx[0][s * 32 + r];
        st[s] = uemb[(size_t)row * 8 + c];
    }
#pragma unroll
    for (int s = 0; s < 8; ++s) {
        int e = s * 32 + r;
        buf[e * 8 + (c ^ (e & 7))] = st[s];
    }
    __syncthreads();

    // own user row out of LDS
    float4 uu[8];
#pragma unroll
    for (int q = 0; q < 8; ++q) uu[q] = buf[t * 8 + (q ^ (t & 7))];

    const f2* Wp = (const f2*)W;       // pair index = grp*128 + j*16 + d
    f2 h2[8];
#pragma unroll
    for (int j = 0; j < 8; ++j) { h2[j].x = W[768 + j]; h2[j].y = 0.0f; }

    // u-term while movie loads are in flight
#pragma unroll
    for (int q = 0; q < 8; ++q) {
        f2 u0; u0.x = uu[q].x; u0.y = uu[q].y;
        f2 u1; u1.x = uu[q].z; u1.y = uu[q].w;
        int d0 = 2 * q, d1 = 2 * q + 1;
#pragma unroll
        for (int j = 0; j < 8; ++j) {
            h2[j] = __builtin_elementwise_fma(u0, Wp[128 + j * 16 + d0], h2[j]);
            h2[j] = __builtin_elementwise_fma(u1, Wp[128 + j * 16 + d1], h2[j]);
        }
    }

    // ---- movie rows: cooperative gather (issued early by scheduler) ----
#pragma unroll
    for (int s = 0; s < 8; ++s) {
        int row = sidx[1][s * 32 + r];
        st[s] = memb[(size_t)row * 8 + c];
    }
    __syncthreads();   // all u-reads from buf done before overwrite
#pragma unroll
    for (int s = 0; s < 8; ++s) {
        int e = s * 32 + r;
        buf[e * 8 + (c ^ (e & 7))] = st[s];
    }
    __syncthreads();

    // own movie row; m-term and u*m-term
#pragma unroll
    for (int q = 0; q < 8; ++q) {
        float4 mv = buf[t * 8 + (q ^ (t & 7))];
        f2 u0; u0.x = uu[q].x; u0.y = uu[q].y;
        f2 u1; u1.x = uu[q].z; u1.y = uu[q].w;
        f2 m0; m0.x = mv.x;    m0.y = mv.y;
        f2 m1; m1.x = mv.z;    m1.y = mv.w;
        f2 p0 = u0 * m0;       // v_pk_mul_f32
        f2 p1 = u1 * m1;
        int d0 = 2 * q, d1 = 2 * q + 1;
#pragma unroll
        for (int j = 0; j < 8; ++j) {
            h2[j] = __builtin_elementwise_fma(p0, Wp[      j * 16 + d0], h2[j]);
            h2[j] = __builtin_elementwise_fma(m0, Wp[256 + j * 16 + d0], h2[j]);
            h2[j] = __builtin_elementwise_fma(p1, Wp[      j * 16 + d1], h2[j]);
            h2[j] = __builtin_elementwise_fma(m1, Wp[256 + j * 16 + d1], h2[j]);
        }
    }

    float z = W[784];
#pragma unroll
    for (int j = 0; j < 8; ++j) {
        float hj = h2[j].x + h2[j].y;
        z = fmaf(fmaxf(hj, 0.0f), W[776 + j], z);
    }

    if (i < n) out[i] = 1.0f / (1.0f + __expf(-z));
}

extern "C" void kernel_launch(void* const* d_in, const int* in_sizes, int n_in,
                              void* d_out, int out_size, void* d_ws, size_t ws_size,
                              hipStream_t stream) {
    const int* users   = (const int*)d_in[0];
    const int* movies  = (const int*)d_in[1];
    const float4* uemb = (const float4*)d_in[2];   // fp32 [1e6, 32]
    const float4* memb = (const float4*)d_in[3];   // fp32 [1e5, 32]
    const float* w1    = (const float*)d_in[4];    // fp32 [8, 96]
    const float* b1    = (const float*)d_in[5];    // fp32 [8]
    const float* w2    = (const float*)d_in[6];    // fp32 [1, 8]
    const float* b2    = (const float*)d_in[7];    // fp32 [1]
    float* ws = (float*)d_ws;
    float* out = (float*)d_out;

    int n = in_sizes[0];

    prep_kernel<<<1, TPB, 0, stream>>>(w1, b1, w2, b2, ws);
    mf_kernel<<<(n + TPB - 1) / TPB, TPB, 0, stream>>>(users, movies, uemb, memb, ws, out, n);
}

// Round 6
// 228.809 us; speedup vs baseline: 1.2593x; 1.2593x over previous
//
#include <hip/hip_runtime.h>
#include <hip/hip_bf16.h>

#define TPB 128

typedef float f2 __attribute__((ext_vector_type(2)));

// Region layout (per block): 2 waves x 8 gather-regions per table.
// Region (w,s) = 8 rows x 128 B, lane-linear (global_load_lds constraint),
// stride 1040 B (16 B pad) so read-phase b128 bank-group = (s+q)&7 -> floor.
#define RSTRIDE 1040
#define NREG    16            // (TPB/64) * 8
#define MOFF    (NREG * RSTRIDE)   // 16640

// ws layout (fp32):
//   W[grp*256 + j*32 + k] = w1[j][grp*32 + k]   grp: 0 = u*m, 1 = u, 2 = m
//   W[768 + j] = b1[j];  W[776 + j] = w2[j];  W[784] = b2
__global__ void prep_kernel(const float* __restrict__ w1,
                            const float* __restrict__ b1,
                            const float* __restrict__ w2,
                            const float* __restrict__ b2,
                            float* __restrict__ W) {
    int t = threadIdx.x;
    for (int i = t; i < 768; i += TPB) {
        int grp = i >> 8;
        int r   = i & 255;
        int j   = r >> 5;
        int k   = r & 31;
        W[i] = w1[j * 96 + grp * 32 + k];
    }
    if (t < 8) W[768 + t] = b1[t];
    if (t < 8) W[776 + t] = w2[t];
    if (t == 0) W[784]    = b2[0];
}

__global__ __launch_bounds__(TPB) void mf_kernel(
    const int* __restrict__ users, const int* __restrict__ movies,
    const char* __restrict__ uemb,   // fp32 [1e6][32] = 128 B rows
    const char* __restrict__ memb,   // fp32 [1e5][32]
    const float* __restrict__ W,
    float* __restrict__ out, int n) {
    __shared__ char lds[2 * MOFF];   // 33280 B

    int t = threadIdx.x;
    int i = blockIdx.x * TPB + t;
    int ic = (i < n) ? i : (n - 1);
    int uidx = users[ic];            // coalesced; element t's indices live in lane t&63 of wave t>>6
    int midx = movies[ic];

    int l    = t & 63;
    int w    = t >> 6;
    int slot = l >> 3;               // row-slot this lane serves in each gather
    int c    = l & 7;                // 16 B chunk this lane fetches

    // 16 row-gathers per wave, all in flight before one barrier.
#pragma unroll
    for (int s = 0; s < 8; ++s) {
        int ru = __shfl(uidx, s * 8 + slot, 64);
        __builtin_amdgcn_global_load_lds(
            (const __attribute__((address_space(1))) void*)(uemb + (size_t)ru * 128 + c * 16),
            (__attribute__((address_space(3))) void*)&lds[(w * 8 + s) * RSTRIDE],
            16, 0, 0);
    }
#pragma unroll
    for (int s = 0; s < 8; ++s) {
        int rm = __shfl(midx, s * 8 + slot, 64);
        __builtin_amdgcn_global_load_lds(
            (const __attribute__((address_space(1))) void*)(memb + (size_t)rm * 128 + c * 16),
            (__attribute__((address_space(3))) void*)&lds[MOFF + (w * 8 + s) * RSTRIDE],
            16, 0, 0);
    }
    __syncthreads();

    // My element's rows: region (w, (t>>3)&7), row-slot t&7.
    const char* urow = &lds[(w * 8 + ((t >> 3) & 7)) * RSTRIDE + (t & 7) * 128];
    const char* mrow = urow + MOFF;

    const f2* Wp = (const f2*)W;     // pair index = grp*128 + j*16 + d
    f2 h2[8];
#pragma unroll
    for (int j = 0; j < 8; ++j) { h2[j].x = W[768 + j]; h2[j].y = 0.0f; }

#pragma unroll
    for (int q = 0; q < 8; ++q) {
        float4 u4 = *(const float4*)(urow + q * 16);
        float4 m4 = *(const float4*)(mrow + q * 16);
        f2 u0; u0.x = u4.x; u0.y = u4.y;
        f2 u1; u1.x = u4.z; u1.y = u4.w;
        f2 m0; m0.x = m4.x; m0.y = m4.y;
        f2 m1; m1.x = m4.z; m1.y = m4.w;
        f2 p0 = u0 * m0;             // v_pk_mul_f32
        f2 p1 = u1 * m1;
        int d0 = 2 * q, d1 = 2 * q + 1;
#pragma unroll
        for (int j = 0; j < 8; ++j) {
            h2[j] = __builtin_elementwise_fma(p0, Wp[      j * 16 + d0], h2[j]);
            h2[j] = __builtin_elementwise_fma(u0, Wp[128 + j * 16 + d0], h2[j]);
            h2[j] = __builtin_elementwise_fma(m0, Wp[256 + j * 16 + d0], h2[j]);
            h2[j] = __builtin_elementwise_fma(p1, Wp[      j * 16 + d1], h2[j]);
            h2[j] = __builtin_elementwise_fma(u1, Wp[128 + j * 16 + d1], h2[j]);
            h2[j] = __builtin_elementwise_fma(m1, Wp[256 + j * 16 + d1], h2[j]);
        }
    }

    float z = W[784];
#pragma unroll
    for (int j = 0; j < 8; ++j) {
        float hj = h2[j].x + h2[j].y;
        z = fmaf(fmaxf(hj, 0.0f), W[776 + j], z);
    }

    if (i < n) out[i] = 1.0f / (1.0f + __expf(-z));
}

extern "C" void kernel_launch(void* const* d_in, const int* in_sizes, int n_in,
                              void* d_out, int out_size, void* d_ws, size_t ws_size,
                              hipStream_t stream) {
    const int* users  = (const int*)d_in[0];
    const int* movies = (const int*)d_in[1];
    const char* uemb  = (const char*)d_in[2];    // fp32 [1e6, 32]
    const char* memb  = (const char*)d_in[3];    // fp32 [1e5, 32]
    const float* w1   = (const float*)d_in[4];   // fp32 [8, 96]
    const float* b1   = (const float*)d_in[5];   // fp32 [8]
    const float* w2   = (const float*)d_in[6];   // fp32 [1, 8]
    const float* b2   = (const float*)d_in[7];   // fp32 [1]
    float* ws = (float*)d_ws;
    float* out = (float*)d_out;

    int n = in_sizes[0];

    prep_kernel<<<1, TPB, 0, stream>>>(w1, b1, w2, b2, ws);
    mf_kernel<<<(n + TPB - 1) / TPB, TPB, 0, stream>>>(users, movies, uemb, memb, ws, out, n);
}